// Round 1
// baseline (11553.432 us; speedup 1.0000x reference)
//
#include <hip/hip_runtime.h>
#include <math.h>

#define HIDDEN 1024
#define SEQ    4096
#define BATCH  4

// ---------------------------------------------------------------------------
// GEMM NT:  C[M,N] = alpha * (A[M,K] @ B[N,K]^T) + bias[col]   (bias optional)
// Both A and B are K-contiguous (row-major with K inner) -> coalesced loads.
// Tiles: 64x64 output per block, BK=16. 256 threads, 4x4 micro-tile/thread.
// LDS rows padded to 20 floats: float4 fragment reads are 16B-aligned and the
// 4-row access stride maps to a free 2-way bank conflict (m136).
// ---------------------------------------------------------------------------
__global__ __launch_bounds__(256)
void gemm_nt_kernel(const float* __restrict__ A, const float* __restrict__ B,
                    const float* __restrict__ bias, float* __restrict__ C,
                    int M, int N, int K, float alpha) {
    __shared__ float As[64][20];
    __shared__ float Bs[64][20];

    const int tid = threadIdx.x;
    const int tx  = tid & 15;        // 0..15 : col group (4 cols each)
    const int ty  = tid >> 4;        // 0..15 : row group (4 rows each)
    const int row0 = blockIdx.y * 64;
    const int col0 = blockIdx.x * 64;

    // staging indices: each thread loads one float4 of A-tile and one of B-tile
    const int lr = tid >> 2;         // 0..63 tile row
    const int lc = (tid & 3) << 2;   // 0,4,8,12 k offset

    const float* Aptr = A + (size_t)(row0 + lr) * K + lc;
    const float* Bptr = B + (size_t)(col0 + lr) * K + lc;

    float acc[4][4] = {};

    for (int k0 = 0; k0 < K; k0 += 16) {
        float4 a4 = *(const float4*)(Aptr + k0);
        float4 b4 = *(const float4*)(Bptr + k0);
        As[lr][lc + 0] = a4.x; As[lr][lc + 1] = a4.y;
        As[lr][lc + 2] = a4.z; As[lr][lc + 3] = a4.w;
        Bs[lr][lc + 0] = b4.x; Bs[lr][lc + 1] = b4.y;
        Bs[lr][lc + 2] = b4.z; Bs[lr][lc + 3] = b4.w;
        __syncthreads();

        #pragma unroll
        for (int kk = 0; kk < 16; kk += 4) {
            float4 ra[4], rb[4];
            #pragma unroll
            for (int i = 0; i < 4; ++i) ra[i] = *(const float4*)&As[ty * 4 + i][kk];
            #pragma unroll
            for (int j = 0; j < 4; ++j) rb[j] = *(const float4*)&Bs[tx * 4 + j][kk];
            #pragma unroll
            for (int i = 0; i < 4; ++i)
                #pragma unroll
                for (int j = 0; j < 4; ++j) {
                    acc[i][j] += ra[i].x * rb[j].x;
                    acc[i][j] += ra[i].y * rb[j].y;
                    acc[i][j] += ra[i].z * rb[j].z;
                    acc[i][j] += ra[i].w * rb[j].w;
                }
        }
        __syncthreads();
    }

    #pragma unroll
    for (int i = 0; i < 4; ++i) {
        const int r = row0 + ty * 4 + i;
        #pragma unroll
        for (int j = 0; j < 4; ++j) {
            const int c = col0 + tx * 4 + j;
            float v = alpha * acc[i][j];
            if (bias) v += bias[c];
            C[(size_t)r * N + c] = v;
        }
    }
}

// ---------------------------------------------------------------------------
// GEMM NN:  C[M,N] = A[M,K] @ B[K,N]     (A is K-contiguous, B is N-contiguous)
// Same 64x64x16 tiling; B tile stored transposed in LDS (BsT[col][k]) so the
// inner loop reads float4 fragments along k for both operands.
// ---------------------------------------------------------------------------
__global__ __launch_bounds__(256)
void gemm_nn_kernel(const float* __restrict__ A, const float* __restrict__ B,
                    float* __restrict__ C, int M, int N, int K) {
    __shared__ float As[64][20];
    __shared__ float BsT[64][20];   // [col][k]

    const int tid = threadIdx.x;
    const int tx  = tid & 15;
    const int ty  = tid >> 4;
    const int row0 = blockIdx.y * 64;
    const int col0 = blockIdx.x * 64;

    const int lr = tid >> 2;         // A tile row 0..63
    const int lc = (tid & 3) << 2;   // A tile k offset
    const int kb = tid >> 4;         // B tile k row 0..15
    const int cb = (tid & 15) << 2;  // B tile col offset (0..60)

    const float* Aptr = A + (size_t)(row0 + lr) * K + lc;
    const float* Bptr = B + (size_t)kb * N + col0 + cb;

    float acc[4][4] = {};

    for (int k0 = 0; k0 < K; k0 += 16) {
        float4 a4 = *(const float4*)(Aptr + k0);
        float4 b4 = *(const float4*)(Bptr + (size_t)k0 * N);
        As[lr][lc + 0] = a4.x; As[lr][lc + 1] = a4.y;
        As[lr][lc + 2] = a4.z; As[lr][lc + 3] = a4.w;
        BsT[cb + 0][kb] = b4.x; BsT[cb + 1][kb] = b4.y;
        BsT[cb + 2][kb] = b4.z; BsT[cb + 3][kb] = b4.w;
        __syncthreads();

        #pragma unroll
        for (int kk = 0; kk < 16; kk += 4) {
            float4 ra[4], rb[4];
            #pragma unroll
            for (int i = 0; i < 4; ++i) ra[i] = *(const float4*)&As[ty * 4 + i][kk];
            #pragma unroll
            for (int j = 0; j < 4; ++j) rb[j] = *(const float4*)&BsT[tx * 4 + j][kk];
            #pragma unroll
            for (int i = 0; i < 4; ++i)
                #pragma unroll
                for (int j = 0; j < 4; ++j) {
                    acc[i][j] += ra[i].x * rb[j].x;
                    acc[i][j] += ra[i].y * rb[j].y;
                    acc[i][j] += ra[i].z * rb[j].z;
                    acc[i][j] += ra[i].w * rb[j].w;
                }
        }
        __syncthreads();
    }

    #pragma unroll
    for (int i = 0; i < 4; ++i) {
        const int r = row0 + ty * 4 + i;
        #pragma unroll
        for (int j = 0; j < 4; ++j) {
            const int c = col0 + tx * 4 + j;
            C[(size_t)r * N + c] = acc[i][j];
        }
    }
}

// ---------------------------------------------------------------------------
// Row softmax over ncol=4096 columns. One 256-thread block per row; each
// thread holds 16 elements in registers (4 x float4, coalesced chunks).
// ---------------------------------------------------------------------------
__global__ __launch_bounds__(256)
void softmax_kernel(float* __restrict__ S, int ncol) {
    const int row = blockIdx.x;
    float* p = S + (size_t)row * ncol;
    const int tid = threadIdx.x;

    float4 v[4];
    float mx = -3.0e38f;
    #pragma unroll
    for (int i = 0; i < 4; ++i) {
        v[i] = *(const float4*)(p + i * 1024 + tid * 4);
        mx = fmaxf(mx, fmaxf(fmaxf(v[i].x, v[i].y), fmaxf(v[i].z, v[i].w)));
    }

    // wave (64-lane) max reduce
    #pragma unroll
    for (int off = 32; off > 0; off >>= 1)
        mx = fmaxf(mx, __shfl_xor(mx, off, 64));

    __shared__ float redmax[4];
    __shared__ float redsum[4];
    const int wave = tid >> 6, lane = tid & 63;
    if (lane == 0) redmax[wave] = mx;
    __syncthreads();
    mx = fmaxf(fmaxf(redmax[0], redmax[1]), fmaxf(redmax[2], redmax[3]));

    float sum = 0.0f;
    #pragma unroll
    for (int i = 0; i < 4; ++i) {
        v[i].x = expf(v[i].x - mx);
        v[i].y = expf(v[i].y - mx);
        v[i].z = expf(v[i].z - mx);
        v[i].w = expf(v[i].w - mx);
        sum += v[i].x + v[i].y + v[i].z + v[i].w;
    }
    #pragma unroll
    for (int off = 32; off > 0; off >>= 1)
        sum += __shfl_xor(sum, off, 64);
    if (lane == 0) redsum[wave] = sum;
    __syncthreads();
    const float total = redsum[0] + redsum[1] + redsum[2] + redsum[3];
    const float inv = 1.0f / total;

    #pragma unroll
    for (int i = 0; i < 4; ++i) {
        v[i].x *= inv; v[i].y *= inv; v[i].z *= inv; v[i].w *= inv;
        *(float4*)(p + i * 1024 + tid * 4) = v[i];
    }
}

// ---------------------------------------------------------------------------
// Launch: QKV projections (one fused M = B*S GEMM each), then per batch:
// scores (NT, alpha=1/32) -> softmax -> PV (NN).
// ws layout (floats): Q[16.7M] | K[16.7M] | V[16.7M] | Sc[16.7M, reused/batch]
// total = 256 MB.
// ---------------------------------------------------------------------------
extern "C" void kernel_launch(void* const* d_in, const int* in_sizes, int n_in,
                              void* d_out, int out_size, void* d_ws, size_t ws_size,
                              hipStream_t stream) {
    const float* X  = (const float*)d_in[0];
    const float* Wq = (const float*)d_in[1];
    const float* bq = (const float*)d_in[2];
    const float* Wk = (const float*)d_in[3];
    const float* bk = (const float*)d_in[4];
    const float* Wv = (const float*)d_in[5];
    const float* bv = (const float*)d_in[6];
    float* out = (float*)d_out;

    const size_t MH = (size_t)BATCH * SEQ * HIDDEN;   // 16,777,216 floats
    float* Q  = (float*)d_ws;
    float* Kp = Q + MH;
    float* V  = Kp + MH;
    float* Sc = V + MH;                               // SEQ*SEQ floats, reused

    const dim3 blk(256);

    // QKV projections: [16384,1024] x [1024,1024]^T
    const dim3 g_qkv(HIDDEN / 64, (BATCH * SEQ) / 64);
    gemm_nt_kernel<<<g_qkv, blk, 0, stream>>>(X, Wq, bq, Q,  BATCH * SEQ, HIDDEN, HIDDEN, 1.0f);
    gemm_nt_kernel<<<g_qkv, blk, 0, stream>>>(X, Wk, bk, Kp, BATCH * SEQ, HIDDEN, HIDDEN, 1.0f);
    gemm_nt_kernel<<<g_qkv, blk, 0, stream>>>(X, Wv, bv, V,  BATCH * SEQ, HIDDEN, HIDDEN, 1.0f);

    const float scale = 1.0f / 32.0f;   // 1/sqrt(1024)
    for (int b = 0; b < BATCH; ++b) {
        const float* Qb = Q  + (size_t)b * SEQ * HIDDEN;
        const float* Kb = Kp + (size_t)b * SEQ * HIDDEN;
        const float* Vb = V  + (size_t)b * SEQ * HIDDEN;
        float* outb = out + (size_t)b * SEQ * HIDDEN;

        const dim3 g_s(SEQ / 64, SEQ / 64);
        gemm_nt_kernel<<<g_s, blk, 0, stream>>>(Qb, Kb, nullptr, Sc, SEQ, SEQ, HIDDEN, scale);

        softmax_kernel<<<dim3(SEQ), blk, 0, stream>>>(Sc, SEQ);

        const dim3 g_pv(HIDDEN / 64, SEQ / 64);
        gemm_nn_kernel<<<g_pv, blk, 0, stream>>>(Sc, Vb, outb, SEQ, HIDDEN, SEQ);
    }
}

// Round 2
// 1386.755 us; speedup vs baseline: 8.3313x; 8.3313x over previous
//
#include <hip/hip_runtime.h>
#include <hip/hip_bf16.h>
#include <math.h>

#define HIDDEN 1024
#define SEQ    4096
#define BATCH  4

typedef __bf16 bf16x8 __attribute__((ext_vector_type(8)));
typedef float  floatx4 __attribute__((ext_vector_type(4)));

// async 16B global->LDS copy (m97: width=16 emits global_load_lds_dwordx4)
__device__ inline void gld16(const void* g, void* l) {
    __builtin_amdgcn_global_load_lds(
        (const __attribute__((address_space(1))) unsigned int*)g,
        (__attribute__((address_space(3))) unsigned int*)l, 16, 0, 0);
}

// ---------------------------------------------------------------------------
// Split-precision bf16 MFMA GEMM (NT): C[M,N] = alpha*(A @ B^T) + bias
// A given as Ah (+Al if PASSES==3) [M,K] bf16, lda elements per row.
// B given as Bh (+Bl)              [N,K] bf16, ldb elements per row.
// PASSES==3: A@B ~= Ah Bh + Ah Bl + Al Bh  (fp32-class accuracy)
// MODE: 0 = fp32 out C[r*N+c]
//       1 = bf16 hi/lo split out (Chi/Clo)
//       2 = bf16 transposed-V out: Chi[(b*N+c)*SEQ + s], b=r>>12, s=r&4095
// Tile: 128x128, BK=32. 256 thr = 4 waves in 2x2, each wave 4x4 16x16 MFMA
// subtiles. LDS tiles [128][32] bf16 contiguous (global_load_lds layout).
// ---------------------------------------------------------------------------
template<int PASSES, int MODE>
__global__ __launch_bounds__(256)
void gemm_split_kernel(const __hip_bfloat16* __restrict__ Ah,
                       const __hip_bfloat16* __restrict__ Al,
                       const __hip_bfloat16* __restrict__ Bh,
                       const __hip_bfloat16* __restrict__ Bl,
                       const float* __restrict__ bias, float alpha,
                       float* __restrict__ Cf,
                       __hip_bfloat16* __restrict__ Chi,
                       __hip_bfloat16* __restrict__ Clo,
                       int M, int N, int K, int lda, int ldb) {
    __shared__ __align__(16) char smem[(PASSES == 3) ? 32768 : 16384];
    char* sAh = smem;                 // 8 KB: 128 rows x 32 bf16
    char* sBh = smem + 8192;
    char* sAl = smem + 16384;         // only PASSES==3
    char* sBl = smem + 24576;

    const int tid  = threadIdx.x;
    const int lane = tid & 63;
    const int w    = tid >> 6;
    const int wm   = w & 1;           // wave row (0..1) -> 64 rows
    const int wn   = w >> 1;          // wave col (0..1) -> 64 cols
    const int quad = lane >> 4;       // 0..3
    const int l16  = lane & 15;

    const int row0 = blockIdx.y * 128;
    const int col0 = blockIdx.x * 128;

    floatx4 acc[4][4];
    #pragma unroll
    for (int i = 0; i < 4; ++i)
        #pragma unroll
        for (int j = 0; j < 4; ++j) acc[i][j] = (floatx4){0.f, 0.f, 0.f, 0.f};

    const bf16x8* pAh = (const bf16x8*)sAh;
    const bf16x8* pBh = (const bf16x8*)sBh;
    const bf16x8* pAl = (const bf16x8*)sAl;
    const bf16x8* pBl = (const bf16x8*)sBl;

    for (int k0 = 0; k0 < K; k0 += 32) {
        // stage: tile = 512 chunks of 16B; chunk n -> row n>>2, col (n&3)*8
        #pragma unroll
        for (int it = 0; it < 2; ++it) {
            const int n = tid + it * 256;
            const size_t ra = (size_t)(row0 + (n >> 2)) * lda + (size_t)k0 + (n & 3) * 8;
            const size_t rb = (size_t)(col0 + (n >> 2)) * ldb + (size_t)k0 + (n & 3) * 8;
            gld16(Ah + ra, sAh + n * 16);
            gld16(Bh + rb, sBh + n * 16);
            if (PASSES == 3) {
                gld16(Al + ra, sAl + n * 16);
                gld16(Bl + rb, sBl + n * 16);
            }
        }
        __syncthreads();

        bf16x8 af[4], afl[4];
        #pragma unroll
        for (int i = 0; i < 4; ++i) {
            const int r = wm * 64 + i * 16 + l16;
            af[i] = pAh[r * 4 + quad];
            if (PASSES == 3) afl[i] = pAl[r * 4 + quad];
        }
        #pragma unroll
        for (int j = 0; j < 4; ++j) {
            const int c = wn * 64 + j * 16 + l16;
            bf16x8 bf = pBh[c * 4 + quad];
            bf16x8 bfl;
            if (PASSES == 3) bfl = pBl[c * 4 + quad];
            #pragma unroll
            for (int i = 0; i < 4; ++i) {
                acc[i][j] = __builtin_amdgcn_mfma_f32_16x16x32_bf16(af[i], bf, acc[i][j], 0, 0, 0);
                if (PASSES == 3) {
                    acc[i][j] = __builtin_amdgcn_mfma_f32_16x16x32_bf16(af[i], bfl, acc[i][j], 0, 0, 0);
                    acc[i][j] = __builtin_amdgcn_mfma_f32_16x16x32_bf16(afl[i], bf, acc[i][j], 0, 0, 0);
                }
            }
        }
        __syncthreads();
    }

    // epilogue: C/D layout col=lane&15, row=quad*4+reg (m89/m91 verified)
    #pragma unroll
    for (int i = 0; i < 4; ++i) {
        const int r0 = row0 + wm * 64 + i * 16 + quad * 4;
        #pragma unroll
        for (int j = 0; j < 4; ++j) {
            const int c = col0 + wn * 64 + j * 16 + l16;
            const float bcol = bias ? bias[c] : 0.0f;
            if (MODE == 0) {
                #pragma unroll
                for (int reg = 0; reg < 4; ++reg)
                    Cf[(size_t)(r0 + reg) * N + c] = alpha * acc[i][j][reg] + bcol;
            } else if (MODE == 1) {
                #pragma unroll
                for (int reg = 0; reg < 4; ++reg) {
                    const float v = acc[i][j][reg] + bcol;
                    const __hip_bfloat16 h = __float2bfloat16(v);
                    Chi[(size_t)(r0 + reg) * N + c] = h;
                    Clo[(size_t)(r0 + reg) * N + c] = __float2bfloat16(v - __bfloat162float(h));
                }
            } else {
                const int bb = r0 >> 12;      // batch  (r0 multiple of 4)
                const int s  = r0 & 4095;     // seq pos
                __hip_bfloat16 t[4];
                #pragma unroll
                for (int reg = 0; reg < 4; ++reg)
                    t[reg] = __float2bfloat16(acc[i][j][reg] + bcol);
                *(uint2*)&Chi[((size_t)bb * N + c) * SEQ + s] = *(const uint2*)t;
            }
        }
    }
}

// ---------------------------------------------------------------------------
// fp32 -> bf16 hi/lo split, float4-vectorized elementwise
// ---------------------------------------------------------------------------
__global__ __launch_bounds__(256)
void split_kernel(const float* __restrict__ in,
                  __hip_bfloat16* __restrict__ hi,
                  __hip_bfloat16* __restrict__ lo) {
    const int i = blockIdx.x * 256 + threadIdx.x;
    const float4 x = ((const float4*)in)[i];
    const float xs[4] = {x.x, x.y, x.z, x.w};
    __hip_bfloat16 h[4], l[4];
    #pragma unroll
    for (int k = 0; k < 4; ++k) {
        h[k] = __float2bfloat16(xs[k]);
        l[k] = __float2bfloat16(xs[k] - __bfloat162float(h[k]));
    }
    ((uint2*)hi)[i] = *(const uint2*)h;
    ((uint2*)lo)[i] = *(const uint2*)l;
}

// ---------------------------------------------------------------------------
// Row softmax over 4096 fp32 columns, writing bf16 IN PLACE over the row
// start (P row stride becomes 8192 bf16 elements = 16KB).
// ---------------------------------------------------------------------------
__global__ __launch_bounds__(256)
void softmax_bf16_kernel(float* __restrict__ S) {
    const int row = blockIdx.x;
    float* p = S + (size_t)row * 4096;
    const int tid = threadIdx.x;

    float4 v[4];
    float mx = -3.0e38f;
    #pragma unroll
    for (int i = 0; i < 4; ++i) {
        v[i] = *(const float4*)(p + i * 1024 + tid * 4);
        mx = fmaxf(mx, fmaxf(fmaxf(v[i].x, v[i].y), fmaxf(v[i].z, v[i].w)));
    }
    #pragma unroll
    for (int off = 32; off > 0; off >>= 1)
        mx = fmaxf(mx, __shfl_xor(mx, off, 64));

    __shared__ float redmax[4];
    __shared__ float redsum[4];
    const int wave = tid >> 6, lane = tid & 63;
    if (lane == 0) redmax[wave] = mx;
    __syncthreads();
    mx = fmaxf(fmaxf(redmax[0], redmax[1]), fmaxf(redmax[2], redmax[3]));

    float sum = 0.0f;
    #pragma unroll
    for (int i = 0; i < 4; ++i) {
        v[i].x = expf(v[i].x - mx);
        v[i].y = expf(v[i].y - mx);
        v[i].z = expf(v[i].z - mx);
        v[i].w = expf(v[i].w - mx);
        sum += v[i].x + v[i].y + v[i].z + v[i].w;
    }
    #pragma unroll
    for (int off = 32; off > 0; off >>= 1)
        sum += __shfl_xor(sum, off, 64);
    if (lane == 0) redsum[wave] = sum;
    __syncthreads();
    const float inv = 1.0f / (redsum[0] + redsum[1] + redsum[2] + redsum[3]);

    __hip_bfloat16* ob = (__hip_bfloat16*)p;   // in-place: reads all done above
    #pragma unroll
    for (int i = 0; i < 4; ++i) {
        __hip_bfloat16 t[4];
        t[0] = __float2bfloat16(v[i].x * inv);
        t[1] = __float2bfloat16(v[i].y * inv);
        t[2] = __float2bfloat16(v[i].z * inv);
        t[3] = __float2bfloat16(v[i].w * inv);
        *(uint2*)(ob + i * 1024 + tid * 4) = *(const uint2*)t;
    }
}

// ---------------------------------------------------------------------------
// ws layout (bytes), total 247.5 MB (round-1 proved ws >= 256 MB):
//   [0, 67.1M)   : Xh | Xl  (33.55M each)  -- after projections reused as Sc
//   [67.1M, ...) : Wqh Wql Wkh Wkl Wvh Wvl (2.097M each)
//   then         : Qh Ql Kh Kl (33.55M each)
//   then         : Vt bf16 [B][H][S] (33.55M)
// ---------------------------------------------------------------------------
extern "C" void kernel_launch(void* const* d_in, const int* in_sizes, int n_in,
                              void* d_out, int out_size, void* d_ws, size_t ws_size,
                              hipStream_t stream) {
    const float* X  = (const float*)d_in[0];
    const float* Wq = (const float*)d_in[1];
    const float* bq = (const float*)d_in[2];
    const float* Wk = (const float*)d_in[3];
    const float* bk = (const float*)d_in[4];
    const float* Wv = (const float*)d_in[5];
    const float* bv = (const float*)d_in[6];
    float* out = (float*)d_out;

    char* ws = (char*)d_ws;
    const size_t MH  = (size_t)BATCH * SEQ * HIDDEN;       // 16,777,216
    const size_t XB  = MH * 2;                             // bf16 bytes: 33,554,432
    const size_t WB  = (size_t)HIDDEN * HIDDEN * 2;        // 2,097,152

    __hip_bfloat16* Xh  = (__hip_bfloat16*)(ws);
    __hip_bfloat16* Xl  = (__hip_bfloat16*)(ws + XB);
    float*          Sc  = (float*)(ws);                    // aliases Xh|Xl
    char* wp = ws + 2 * XB;
    __hip_bfloat16* Wqh = (__hip_bfloat16*)(wp);
    __hip_bfloat16* Wql = (__hip_bfloat16*)(wp + WB);
    __hip_bfloat16* Wkh = (__hip_bfloat16*)(wp + 2 * WB);
    __hip_bfloat16* Wkl = (__hip_bfloat16*)(wp + 3 * WB);
    __hip_bfloat16* Wvh = (__hip_bfloat16*)(wp + 4 * WB);
    __hip_bfloat16* Wvl = (__hip_bfloat16*)(wp + 5 * WB);
    char* qp = wp + 6 * WB;
    __hip_bfloat16* Qh  = (__hip_bfloat16*)(qp);
    __hip_bfloat16* Ql  = (__hip_bfloat16*)(qp + XB);
    __hip_bfloat16* Kh  = (__hip_bfloat16*)(qp + 2 * XB);
    __hip_bfloat16* Kl  = (__hip_bfloat16*)(qp + 3 * XB);
    __hip_bfloat16* Vt  = (__hip_bfloat16*)(qp + 4 * XB);  // [B][H][S]

    const dim3 blk(256);

    // 1. splits
    split_kernel<<<dim3(16384), blk, 0, stream>>>(X, Xh, Xl);
    split_kernel<<<dim3(1024),  blk, 0, stream>>>(Wq, Wqh, Wql);
    split_kernel<<<dim3(1024),  blk, 0, stream>>>(Wk, Wkh, Wkl);
    split_kernel<<<dim3(1024),  blk, 0, stream>>>(Wv, Wvh, Wvl);

    // 2. projections: [16384,1024] x [1024,1024]^T, 3-pass split
    const dim3 g_proj(HIDDEN / 128, (BATCH * SEQ) / 128);
    gemm_split_kernel<3, 1><<<g_proj, blk, 0, stream>>>(
        Xh, Xl, Wqh, Wql, bq, 1.0f, nullptr, Qh, Ql,
        BATCH * SEQ, HIDDEN, HIDDEN, HIDDEN, HIDDEN);
    gemm_split_kernel<3, 1><<<g_proj, blk, 0, stream>>>(
        Xh, Xl, Wkh, Wkl, bk, 1.0f, nullptr, Kh, Kl,
        BATCH * SEQ, HIDDEN, HIDDEN, HIDDEN, HIDDEN);
    gemm_split_kernel<3, 2><<<g_proj, blk, 0, stream>>>(
        Xh, Xl, Wvh, Wvl, bv, 1.0f, nullptr, Vt, nullptr,
        BATCH * SEQ, HIDDEN, HIDDEN, HIDDEN, HIDDEN);

    // 3. per batch: scores -> softmax(->bf16 in place) -> PV
    const float scale = 1.0f / 32.0f;
    for (int b = 0; b < BATCH; ++b) {
        const size_t qoff = (size_t)b * SEQ * HIDDEN;
        gemm_split_kernel<3, 0><<<dim3(SEQ / 128, SEQ / 128), blk, 0, stream>>>(
            Qh + qoff, Ql + qoff, Kh + qoff, Kl + qoff, nullptr, scale,
            Sc, nullptr, nullptr, SEQ, SEQ, HIDDEN, HIDDEN, HIDDEN);

        softmax_bf16_kernel<<<dim3(SEQ), blk, 0, stream>>>(Sc);

        // PV: A = P bf16 (row stride 8192 elems), B = Vt[b] [1024][4096]
        gemm_split_kernel<1, 0><<<dim3(HIDDEN / 128, SEQ / 128), blk, 0, stream>>>(
            (const __hip_bfloat16*)Sc, nullptr,
            Vt + (size_t)b * HIDDEN * SEQ, nullptr, nullptr, 1.0f,
            out + qoff, nullptr, nullptr, SEQ, HIDDEN, SEQ, 2 * SEQ, SEQ);
    }
}

// Round 3
// 985.885 us; speedup vs baseline: 11.7188x; 1.4066x over previous
//
#include <hip/hip_runtime.h>
#include <math.h>

#define HIDDEN 1024
#define SEQ    4096
#define BATCH  4

typedef _Float16 f16x8 __attribute__((ext_vector_type(8)));
typedef float    floatx4 __attribute__((ext_vector_type(4)));

// async 16B global->LDS copy (m97: width=16 emits global_load_lds_dwordx4)
__device__ inline void gld16(const void* g, void* l) {
    __builtin_amdgcn_global_load_lds(
        (const __attribute__((address_space(1))) unsigned int*)g,
        (__attribute__((address_space(3))) unsigned int*)l, 16, 0, 0);
}

// ---------------------------------------------------------------------------
// fp16 MFMA GEMM (NT): C[M,N] = alpha*(A @ B^T) + bias
// A [M,K] fp16 (lda elems/row), B [N,K] fp16 (ldb elems/row).
// MODE: 0 = fp32 out Cf[r*N+c]
//       1 = fp16 out Ch[r*N+c]            (projection Q/K)
//       2 = fp16 transposed-V out: Ch[(b*N+c)*SEQ + s], b=r>>12, s=r&4095
// Tile 128x128, BK=32, 256 thr = 4 waves (2x2), wave = 4x4 16x16x32 MFMAs.
// LDS: 16B chunks; chunk (row r, kchunk c) stored at pos r*4 + (c^((r>>1)&3))
// -- XOR swizzle applied on the GLOBAL source (global_load_lds dest is fixed
// base+lane*16), so fragment ds_read_b128 phases cover all 8 bank groups
// with 2 lanes each (2-way = free, m136).
// ---------------------------------------------------------------------------
template<int MODE>
__global__ __launch_bounds__(256)
void gemm_f16_kernel(const _Float16* __restrict__ A,
                     const _Float16* __restrict__ B,
                     const float* __restrict__ bias, float alpha,
                     float* __restrict__ Cf, _Float16* __restrict__ Ch,
                     int M, int N, int K, int lda, int ldb) {
    __shared__ __align__(16) char smem[16384];
    char* sA = smem;          // 8 KB: 128 rows x 32 f16 (swizzled chunks)
    char* sB = smem + 8192;

    const int tid  = threadIdx.x;
    const int lane = tid & 63;
    const int w    = tid >> 6;
    const int wm   = w & 1;           // wave row -> 64 rows
    const int wn   = w >> 1;          // wave col -> 64 cols
    const int quad = lane >> 4;       // 0..3 (= k-chunk index)
    const int l16  = lane & 15;
    const int swz  = (l16 >> 1) & 3;  // row-derived swizzle bits (i*16,wm*64 don't affect)

    const int row0 = blockIdx.y * 128;
    const int col0 = blockIdx.x * 128;

    floatx4 acc[4][4];
    #pragma unroll
    for (int i = 0; i < 4; ++i)
        #pragma unroll
        for (int j = 0; j < 4; ++j) acc[i][j] = (floatx4){0.f, 0.f, 0.f, 0.f};

    const f16x8* pA = (const f16x8*)sA;
    const f16x8* pB = (const f16x8*)sB;

    // per-thread staging chunk coords (2 chunks per tile per array)
    int   srow[2], scol[2];
    #pragma unroll
    for (int it = 0; it < 2; ++it) {
        const int n = tid + it * 256;
        srow[it] = n >> 2;
        scol[it] = (n & 3) ^ ((srow[it] >> 1) & 3);
    }

    for (int k0 = 0; k0 < K; k0 += 32) {
        #pragma unroll
        for (int it = 0; it < 2; ++it) {
            const int n = tid + it * 256;
            const size_t ga = (size_t)(row0 + srow[it]) * lda + (size_t)k0 + scol[it] * 8;
            const size_t gb = (size_t)(col0 + srow[it]) * ldb + (size_t)k0 + scol[it] * 8;
            gld16(A + ga, sA + n * 16);
            gld16(B + gb, sB + n * 16);
        }
        __syncthreads();

        f16x8 af[4];
        #pragma unroll
        for (int i = 0; i < 4; ++i) {
            const int r = wm * 64 + i * 16 + l16;
            af[i] = pA[r * 4 + (quad ^ swz)];
        }
        #pragma unroll
        for (int j = 0; j < 4; ++j) {
            const int c = wn * 64 + j * 16 + l16;
            const f16x8 bf = pB[c * 4 + (quad ^ swz)];
            #pragma unroll
            for (int i = 0; i < 4; ++i)
                acc[i][j] = __builtin_amdgcn_mfma_f32_16x16x32_f16(af[i], bf, acc[i][j], 0, 0, 0);
        }
        __syncthreads();
    }

    // epilogue: C/D layout col=lane&15, row=quad*4+reg (m89/m91, dtype-indep)
    #pragma unroll
    for (int i = 0; i < 4; ++i) {
        const int r0 = row0 + wm * 64 + i * 16 + quad * 4;
        #pragma unroll
        for (int j = 0; j < 4; ++j) {
            const int c = col0 + wn * 64 + j * 16 + l16;
            const float bcol = bias ? bias[c] : 0.0f;
            if (MODE == 0) {
                #pragma unroll
                for (int reg = 0; reg < 4; ++reg)
                    Cf[(size_t)(r0 + reg) * N + c] = alpha * acc[i][j][reg] + bcol;
            } else if (MODE == 1) {
                #pragma unroll
                for (int reg = 0; reg < 4; ++reg)
                    Ch[(size_t)(r0 + reg) * N + c] = (_Float16)(acc[i][j][reg] + bcol);
            } else {
                const int bb = r0 >> 12;      // batch (r0 multiple of 4)
                const int s  = r0 & 4095;     // seq pos
                _Float16 t[4];
                #pragma unroll
                for (int reg = 0; reg < 4; ++reg)
                    t[reg] = (_Float16)(acc[i][j][reg] + bcol);
                *(uint2*)&Ch[((size_t)bb * N + c) * SEQ + s] = *(const uint2*)t;
            }
        }
    }
}

// ---------------------------------------------------------------------------
// fp32 -> fp16 cast, float4-vectorized
// ---------------------------------------------------------------------------
__global__ __launch_bounds__(256)
void cast_f16_kernel(const float* __restrict__ in, _Float16* __restrict__ out) {
    const int i = blockIdx.x * 256 + threadIdx.x;
    const float4 x = ((const float4*)in)[i];
    _Float16 h[4] = {(_Float16)x.x, (_Float16)x.y, (_Float16)x.z, (_Float16)x.w};
    ((uint2*)out)[i] = *(const uint2*)h;
}

// ---------------------------------------------------------------------------
// Row softmax over 4096 fp32 cols; writes fp16 IN PLACE over the row start
// (P row stride becomes 8192 fp16 elements = 16 KB).
// ---------------------------------------------------------------------------
__global__ __launch_bounds__(256)
void softmax_f16_kernel(float* __restrict__ S) {
    const int row = blockIdx.x;
    float* p = S + (size_t)row * 4096;
    const int tid = threadIdx.x;

    float4 v[4];
    float mx = -3.0e38f;
    #pragma unroll
    for (int i = 0; i < 4; ++i) {
        v[i] = *(const float4*)(p + i * 1024 + tid * 4);
        mx = fmaxf(mx, fmaxf(fmaxf(v[i].x, v[i].y), fmaxf(v[i].z, v[i].w)));
    }
    #pragma unroll
    for (int off = 32; off > 0; off >>= 1)
        mx = fmaxf(mx, __shfl_xor(mx, off, 64));

    __shared__ float redmax[4];
    __shared__ float redsum[4];
    const int wave = tid >> 6, lane = tid & 63;
    if (lane == 0) redmax[wave] = mx;
    __syncthreads();
    mx = fmaxf(fmaxf(redmax[0], redmax[1]), fmaxf(redmax[2], redmax[3]));

    float sum = 0.0f;
    #pragma unroll
    for (int i = 0; i < 4; ++i) {
        v[i].x = expf(v[i].x - mx);
        v[i].y = expf(v[i].y - mx);
        v[i].z = expf(v[i].z - mx);
        v[i].w = expf(v[i].w - mx);
        sum += v[i].x + v[i].y + v[i].z + v[i].w;
    }
    #pragma unroll
    for (int off = 32; off > 0; off >>= 1)
        sum += __shfl_xor(sum, off, 64);
    if (lane == 0) redsum[wave] = sum;
    __syncthreads();
    const float inv = 1.0f / (redsum[0] + redsum[1] + redsum[2] + redsum[3]);

    _Float16* ob = (_Float16*)p;   // in-place: all reads done above
    #pragma unroll
    for (int i = 0; i < 4; ++i) {
        _Float16 t[4] = {(_Float16)(v[i].x * inv), (_Float16)(v[i].y * inv),
                         (_Float16)(v[i].z * inv), (_Float16)(v[i].w * inv)};
        *(uint2*)(ob + i * 1024 + tid * 4) = *(const uint2*)t;
    }
}

// ---------------------------------------------------------------------------
// ws layout (bytes), total ~207 MB (<= 247 MB proven in earlier rounds):
//   [0, 67.1M)  : Sc fp32 (per-batch scores, reused)
//   then        : Xh fp16 33.5M | Wqh Wkh Wvh 2.1M each
//   then        : Qh Kh fp16 33.5M each | Vt fp16 [B][H][S] 33.5M
// ---------------------------------------------------------------------------
extern "C" void kernel_launch(void* const* d_in, const int* in_sizes, int n_in,
                              void* d_out, int out_size, void* d_ws, size_t ws_size,
                              hipStream_t stream) {
    const float* X  = (const float*)d_in[0];
    const float* Wq = (const float*)d_in[1];
    const float* bq = (const float*)d_in[2];
    const float* Wk = (const float*)d_in[3];
    const float* bk = (const float*)d_in[4];
    const float* Wv = (const float*)d_in[5];
    const float* bv = (const float*)d_in[6];
    float* out = (float*)d_out;

    char* ws = (char*)d_ws;
    const size_t MH = (size_t)BATCH * SEQ * HIDDEN;      // 16,777,216
    const size_t ScB = (size_t)SEQ * SEQ * 4;            // 67,108,864
    const size_t XB  = MH * 2;                           // 33,554,432
    const size_t WB  = (size_t)HIDDEN * HIDDEN * 2;      // 2,097,152

    float*    Sc  = (float*)ws;
    _Float16* Xh  = (_Float16*)(ws + ScB);
    _Float16* Wqh = (_Float16*)(ws + ScB + XB);
    _Float16* Wkh = (_Float16*)(ws + ScB + XB + WB);
    _Float16* Wvh = (_Float16*)(ws + ScB + XB + 2 * WB);
    _Float16* Qh  = (_Float16*)(ws + ScB + XB + 3 * WB);
    _Float16* Kh  = (_Float16*)(ws + ScB + 2 * XB + 3 * WB);
    _Float16* Vt  = (_Float16*)(ws + ScB + 3 * XB + 3 * WB);  // [B][H][S]

    const dim3 blk(256);

    // 1. casts
    cast_f16_kernel<<<dim3(16384), blk, 0, stream>>>(X,  Xh);
    cast_f16_kernel<<<dim3(1024),  blk, 0, stream>>>(Wq, Wqh);
    cast_f16_kernel<<<dim3(1024),  blk, 0, stream>>>(Wk, Wkh);
    cast_f16_kernel<<<dim3(1024),  blk, 0, stream>>>(Wv, Wvh);

    // 2. projections: [16384,1024] x [1024,1024]^T
    const dim3 g_proj(HIDDEN / 128, (BATCH * SEQ) / 128);
    gemm_f16_kernel<1><<<g_proj, blk, 0, stream>>>(
        Xh, Wqh, bq, 1.0f, nullptr, Qh, BATCH * SEQ, HIDDEN, HIDDEN, HIDDEN, HIDDEN);
    gemm_f16_kernel<1><<<g_proj, blk, 0, stream>>>(
        Xh, Wkh, bk, 1.0f, nullptr, Kh, BATCH * SEQ, HIDDEN, HIDDEN, HIDDEN, HIDDEN);
    gemm_f16_kernel<2><<<g_proj, blk, 0, stream>>>(
        Xh, Wvh, bv, 1.0f, nullptr, Vt, BATCH * SEQ, HIDDEN, HIDDEN, HIDDEN, HIDDEN);

    // 3. per batch: scores -> softmax(->fp16 in place) -> PV
    const float scale = 1.0f / 32.0f;
    for (int b = 0; b < BATCH; ++b) {
        const size_t qoff = (size_t)b * SEQ * HIDDEN;
        gemm_f16_kernel<0><<<dim3(SEQ / 128, SEQ / 128), blk, 0, stream>>>(
            Qh + qoff, Kh + qoff, nullptr, scale, Sc, nullptr,
            SEQ, SEQ, HIDDEN, HIDDEN, HIDDEN);

        softmax_f16_kernel<<<dim3(SEQ), blk, 0, stream>>>(Sc);

        // PV: A = P fp16 (row stride 8192 elems), B = Vt[b] [1024][4096]
        gemm_f16_kernel<0><<<dim3(HIDDEN / 128, SEQ / 128), blk, 0, stream>>>(
            (const _Float16*)Sc, Vt + (size_t)b * HIDDEN * SEQ, nullptr, 1.0f,
            out + qoff, nullptr, SEQ, HIDDEN, SEQ, 2 * SEQ, SEQ);
    }
}

// Round 4
// 702.639 us; speedup vs baseline: 16.4429x; 1.4031x over previous
//
#include <hip/hip_runtime.h>
#include <math.h>

#define HIDDEN 1024
#define SEQ    4096
#define BATCH  4

typedef _Float16 f16x8 __attribute__((ext_vector_type(8)));
typedef float    floatx4 __attribute__((ext_vector_type(4)));

// async 16B global->LDS copy (m97: width=16 emits global_load_lds_dwordx4)
__device__ inline void gld16(const void* g, void* l) {
    __builtin_amdgcn_global_load_lds(
        (const __attribute__((address_space(1))) unsigned int*)g,
        (__attribute__((address_space(3))) unsigned int*)l, 16, 0, 0);
}

// ---------------------------------------------------------------------------
// fp16 MFMA GEMM (NT core: C = A @ B^T), 128x128 tile, BK=32, 4 waves (2x2),
// LDS chunk-XOR swizzle on the GLOBAL source (round-3: bank conflicts = 0).
//
// MODE 5: fused QKV projection. grid (24,128,1). A=Xh [16384,1024].
//         B rows 0..3071 map to Wq/Wk/Wv by col0>>10 (uniform per block).
//         which<2 -> Qo/Ko[r*1024+cl] fp16; which==2 -> Vt[(b*1024+cl)*4096+s].
// MODE 3: QK scores. grid (32,32,4). z = batch. Writes E = fp16 exp(alpha*s-4)
//         and atomicAdds row partial sums into Lsum[z*4096+row].
// MODE 4: PV. grid (8,32,4). A=E (lda 4096), B=Vt[z] (ldb 4096).
//         Cf[r*1024+c] = acc / Lsum[row]  (fp32 out).
// ---------------------------------------------------------------------------
template<int MODE>
__global__ __launch_bounds__(256)
void gemm_kernel(const _Float16* __restrict__ A,
                 const _Float16* __restrict__ Bq,
                 const _Float16* __restrict__ Bk,
                 const _Float16* __restrict__ Bv,
                 const float* __restrict__ bq,
                 const float* __restrict__ bk,
                 const float* __restrict__ bv,
                 float alpha,
                 float* __restrict__ Cf,
                 _Float16* __restrict__ Eo,
                 _Float16* __restrict__ Qo,
                 _Float16* __restrict__ Ko,
                 _Float16* __restrict__ Vo,
                 float* __restrict__ Lsum,
                 int K, int lda, int ldb) {
    __shared__ __align__(16) char smem[16384];
    char* sA = smem;          // 8 KB: 128 rows x 32 f16, swizzled 16B chunks
    char* sB = smem + 8192;

    const int tid  = threadIdx.x;
    const int lane = tid & 63;
    const int w    = tid >> 6;
    const int wm   = w & 1;
    const int wn   = w >> 1;
    const int quad = lane >> 4;
    const int l16  = lane & 15;
    const int swz  = (l16 >> 1) & 3;

    const int row0 = blockIdx.y * 128;
    const int col0 = blockIdx.x * 128;
    const int bz   = blockIdx.z;

    // batch-relative base pointers
    if (MODE == 3) {
        A    += (size_t)bz * SEQ * HIDDEN;
        Bq   += (size_t)bz * SEQ * HIDDEN;
        Eo   += (size_t)bz * SEQ * SEQ;
        Lsum += (size_t)bz * SEQ;
    } else if (MODE == 4) {
        A    += (size_t)bz * SEQ * SEQ;
        Bq   += (size_t)bz * HIDDEN * SEQ;
        Cf   += (size_t)bz * SEQ * HIDDEN;
        Lsum += (size_t)bz * SEQ;
    }

    // B operand source + column base (MODE 5 picks one of 3 weights; uniform)
    const _Float16* Bsrc = Bq;
    int colbase = col0;
    int which = 0;
    if (MODE == 5) {
        which = col0 >> 10;
        Bsrc = (which == 0) ? Bq : (which == 1) ? Bk : Bv;
        colbase = col0 & 1023;
    }

    floatx4 acc[4][4];
    #pragma unroll
    for (int i = 0; i < 4; ++i)
        #pragma unroll
        for (int j = 0; j < 4; ++j) acc[i][j] = (floatx4){0.f, 0.f, 0.f, 0.f};

    const f16x8* pA = (const f16x8*)sA;
    const f16x8* pB = (const f16x8*)sB;

    int srow[2], scol[2];
    #pragma unroll
    for (int it = 0; it < 2; ++it) {
        const int n = tid + it * 256;
        srow[it] = n >> 2;
        scol[it] = (n & 3) ^ ((srow[it] >> 1) & 3);
    }

    for (int k0 = 0; k0 < K; k0 += 32) {
        #pragma unroll
        for (int it = 0; it < 2; ++it) {
            const int n = tid + it * 256;
            const size_t ga = (size_t)(row0 + srow[it]) * lda + (size_t)k0 + scol[it] * 8;
            const size_t gb = (size_t)(colbase + srow[it]) * ldb + (size_t)k0 + scol[it] * 8;
            gld16(A + ga, sA + n * 16);
            gld16(Bsrc + gb, sB + n * 16);
        }
        __syncthreads();

        f16x8 af[4];
        #pragma unroll
        for (int i = 0; i < 4; ++i) {
            const int r = wm * 64 + i * 16 + l16;
            af[i] = pA[r * 4 + (quad ^ swz)];
        }
        #pragma unroll
        for (int j = 0; j < 4; ++j) {
            const int c = wn * 64 + j * 16 + l16;
            const f16x8 bf = pB[c * 4 + (quad ^ swz)];
            #pragma unroll
            for (int i = 0; i < 4; ++i)
                acc[i][j] = __builtin_amdgcn_mfma_f32_16x16x32_f16(af[i], bf, acc[i][j], 0, 0, 0);
        }
        __syncthreads();
    }

    // ---- epilogue (C/D layout: col=lane&15, row=quad*4+reg) ----
    #pragma unroll
    for (int i = 0; i < 4; ++i) {
        const int r0l = wm * 64 + i * 16 + quad * 4;     // row in tile
        const int r0  = row0 + r0l;                      // global row

        float rp[4] = {0.f, 0.f, 0.f, 0.f};             // MODE 3 row partials

        #pragma unroll
        for (int j = 0; j < 4; ++j) {
            const int cl = (MODE == 5 ? colbase : col0) + wn * 64 + j * 16 + l16;

            if (MODE == 5) {
                const float bcol = (which == 0 ? bq : which == 1 ? bk : bv)[cl];
                if (which < 2) {
                    _Float16* O = (which == 0) ? Qo : Ko;
                    #pragma unroll
                    for (int reg = 0; reg < 4; ++reg)
                        O[(size_t)(r0 + reg) * HIDDEN + cl] =
                            (_Float16)(acc[i][j][reg] + bcol);
                } else {
                    const int bb = r0 >> 12;
                    const int s  = r0 & 4095;
                    _Float16 t[4];
                    #pragma unroll
                    for (int reg = 0; reg < 4; ++reg)
                        t[reg] = (_Float16)(acc[i][j][reg] + bcol);
                    *(uint2*)&Vo[((size_t)bb * HIDDEN + cl) * SEQ + s] = *(const uint2*)t;
                }
            } else if (MODE == 3) {
                #pragma unroll
                for (int reg = 0; reg < 4; ++reg) {
                    const float v = expf(alpha * acc[i][j][reg] - 4.0f);
                    const _Float16 vh = (_Float16)v;
                    Eo[(size_t)(r0 + reg) * SEQ + cl] = vh;
                    rp[reg] += (float)vh;
                }
            } else {  // MODE 4
                #pragma unroll
                for (int reg = 0; reg < 4; ++reg)
                    Cf[(size_t)(r0 + reg) * HIDDEN + cl] =
                        acc[i][j][reg] * (1.0f / Lsum[r0 + reg]);
            }
        }

        if (MODE == 3) {
            // reduce partials over the 16 lanes of this quad (same rows)
            #pragma unroll
            for (int off = 1; off < 16; off <<= 1)
                #pragma unroll
                for (int reg = 0; reg < 4; ++reg)
                    rp[reg] += __shfl_xor(rp[reg], off, 64);
            if (l16 == 0)
                #pragma unroll
                for (int reg = 0; reg < 4; ++reg)
                    atomicAdd(&Lsum[r0 + reg], rp[reg]);
        }
    }
}

// ---------------------------------------------------------------------------
// fp32 -> fp16 cast, float4-vectorized
// ---------------------------------------------------------------------------
__global__ __launch_bounds__(256)
void cast_f16_kernel(const float* __restrict__ in, _Float16* __restrict__ out) {
    const int i = blockIdx.x * 256 + threadIdx.x;
    const float4 x = ((const float4*)in)[i];
    _Float16 h[4] = {(_Float16)x.x, (_Float16)x.y, (_Float16)x.z, (_Float16)x.w};
    ((uint2*)out)[i] = *(const uint2*)h;
}

// ---------------------------------------------------------------------------
// ws layout (bytes), total ~235 MB (round-1 proved ws >= 256 MiB):
//   [0, 134.2M) : E fp16 [B][S][S]   -- during proj phase the head of this
//                 region holds Xh (33.5M) + Wq/Wk/Wv fp16 (2.1M each), dead
//                 before E is written.
//   then        : Qh 33.5M | Kh 33.5M | Vt [B][H][S] 33.5M | Lsum 64K
// ---------------------------------------------------------------------------
extern "C" void kernel_launch(void* const* d_in, const int* in_sizes, int n_in,
                              void* d_out, int out_size, void* d_ws, size_t ws_size,
                              hipStream_t stream) {
    const float* X  = (const float*)d_in[0];
    const float* Wq = (const float*)d_in[1];
    const float* bq = (const float*)d_in[2];
    const float* Wk = (const float*)d_in[3];
    const float* bk = (const float*)d_in[4];
    const float* Wv = (const float*)d_in[5];
    const float* bv = (const float*)d_in[6];
    float* out = (float*)d_out;

    char* ws = (char*)d_ws;
    const size_t EB = (size_t)BATCH * SEQ * SEQ * 2;     // 134,217,728
    const size_t XB = (size_t)BATCH * SEQ * HIDDEN * 2;  // 33,554,432
    const size_t WB = (size_t)HIDDEN * HIDDEN * 2;       // 2,097,152

    _Float16* E   = (_Float16*)ws;
    _Float16* Xh  = (_Float16*)ws;                       // aliases E head
    _Float16* Wqh = (_Float16*)(ws + XB);
    _Float16* Wkh = (_Float16*)(ws + XB + WB);
    _Float16* Wvh = (_Float16*)(ws + XB + 2 * WB);
    _Float16* Qh  = (_Float16*)(ws + EB);
    _Float16* Kh  = (_Float16*)(ws + EB + XB);
    _Float16* Vt  = (_Float16*)(ws + EB + 2 * XB);       // [B][H][S]
    float*    Lsum= (float*)   (ws + EB + 3 * XB);       // [B][S]

    const dim3 blk(256);

    // 1. casts
    cast_f16_kernel<<<dim3(16384), blk, 0, stream>>>(X,  Xh);
    cast_f16_kernel<<<dim3(1024),  blk, 0, stream>>>(Wq, Wqh);
    cast_f16_kernel<<<dim3(1024),  blk, 0, stream>>>(Wk, Wkh);
    cast_f16_kernel<<<dim3(1024),  blk, 0, stream>>>(Wv, Wvh);

    // zero the softmax-denominator accumulators
    hipMemsetAsync(Lsum, 0, (size_t)BATCH * SEQ * sizeof(float), stream);

    // 2. fused QKV projection: [16384,1024] x [3072,1024]^T in one dispatch
    gemm_kernel<5><<<dim3(24, 128, 1), blk, 0, stream>>>(
        Xh, Wqh, Wkh, Wvh, bq, bk, bv, 1.0f,
        nullptr, nullptr, Qh, Kh, Vt, nullptr,
        HIDDEN, HIDDEN, HIDDEN);

    // 3. QK^T -> exp -> E (fp16) + row sums, all batches in one dispatch
    gemm_kernel<3><<<dim3(32, 32, 4), blk, 0, stream>>>(
        Qh, Kh, nullptr, nullptr, nullptr, nullptr, nullptr, 1.0f / 32.0f,
        nullptr, E, nullptr, nullptr, nullptr, Lsum,
        HIDDEN, HIDDEN, HIDDEN);

    // 4. PV with 1/Lsum scaling, all batches in one dispatch
    gemm_kernel<4><<<dim3(8, 32, 4), blk, 0, stream>>>(
        E, Vt, nullptr, nullptr, nullptr, nullptr, nullptr, 1.0f,
        out, nullptr, nullptr, nullptr, nullptr, Lsum,
        SEQ, SEQ, SEQ);
}

// Round 5
// 676.010 us; speedup vs baseline: 17.0906x; 1.0394x over previous
//
#include <hip/hip_runtime.h>
#include <math.h>

#define HIDDEN 1024
#define SEQ    4096
#define BATCH  4

typedef _Float16 f16x8 __attribute__((ext_vector_type(8)));
typedef float    floatx4 __attribute__((ext_vector_type(4)));

// async 16B global->LDS copy (m97: width=16 emits global_load_lds_dwordx4)
__device__ inline void gld16(const void* g, void* l) {
    __builtin_amdgcn_global_load_lds(
        (const __attribute__((address_space(1))) unsigned int*)g,
        (__attribute__((address_space(3))) unsigned int*)l, 16, 0, 0);
}

// ---------------------------------------------------------------------------
// fp16 MFMA GEMM (NT core: C = A @ B^T), 256x256 tile, BK=32, 512 threads =
// 8 waves arranged 4(row)x2(col); wave tile 64x128 = 4x8 of 16x16x32 MFMAs.
//   - LDS intensity: 12 ds_read_b128 per 32 MFMA = 43.7 FLOP/LDS-byte
//     (vs 32 at 64x64 wave tiles) -> LDS ceiling ~55% MfmaUtil.
//   - LLC demand halves vs 128x128 tiles (re-read factor 8->4 / 32->16).
// LDS chunk-XOR swizzle on the GLOBAL source (round-3 proved 0 conflicts).
//
// MODE 5: fused QKV projection. grid (12,64,1). A=Xh [16384,1024].
//         which = col0>>10 picks Wq/Wk/Wv (uniform per block).
//         which<2 -> Qo/Ko[r*1024+cl] fp16; which==2 -> Vt[(b*1024+cl)*4096+s].
// MODE 3: QK scores. grid (16,16,4), z=batch. Writes E = fp16 exp(alpha*s-4),
//         atomicAdds row sums into Lsum[z*4096+row].
// MODE 4: PV. grid (4,16,4). A=E (lda 4096), B=Vt[z] (ldb 4096).
//         Cf[r*1024+c] = acc / Lsum[row] (fp32).
// ---------------------------------------------------------------------------
template<int MODE>
__global__ __launch_bounds__(512, 2)
void gemm256_kernel(const _Float16* __restrict__ A,
                    const _Float16* __restrict__ Bq,
                    const _Float16* __restrict__ Bk,
                    const _Float16* __restrict__ Bv,
                    const float* __restrict__ bq,
                    const float* __restrict__ bk,
                    const float* __restrict__ bv,
                    float alpha,
                    float* __restrict__ Cf,
                    _Float16* __restrict__ Eo,
                    _Float16* __restrict__ Qo,
                    _Float16* __restrict__ Ko,
                    _Float16* __restrict__ Vo,
                    float* __restrict__ Lsum,
                    int K, int lda, int ldb) {
    __shared__ __align__(16) char smem[32768];
    char* sA = smem;            // 16 KB: 256 rows x 32 f16, swizzled 16B chunks
    char* sB = smem + 16384;

    const int tid  = threadIdx.x;
    const int lane = tid & 63;
    const int w    = tid >> 6;        // 0..7
    const int wr   = w & 3;           // wave row -> 64 rows each
    const int wc   = w >> 2;          // wave col -> 128 cols each
    const int quad = lane >> 4;
    const int l16  = lane & 15;
    const int swz  = (l16 >> 1) & 3;  // row bits 1-2 come from l16 only

    const int row0 = blockIdx.y * 256;
    const int col0 = blockIdx.x * 256;
    const int bz   = blockIdx.z;

    if (MODE == 3) {
        A    += (size_t)bz * SEQ * HIDDEN;
        Bq   += (size_t)bz * SEQ * HIDDEN;
        Eo   += (size_t)bz * SEQ * SEQ;
        Lsum += (size_t)bz * SEQ;
    } else if (MODE == 4) {
        A    += (size_t)bz * SEQ * SEQ;
        Bq   += (size_t)bz * HIDDEN * SEQ;
        Cf   += (size_t)bz * SEQ * HIDDEN;
        Lsum += (size_t)bz * SEQ;
    }

    const _Float16* Bsrc = Bq;
    int colbase = col0;
    int which = 0;
    if (MODE == 5) {
        which = col0 >> 10;
        Bsrc = (which == 0) ? Bq : (which == 1) ? Bk : Bv;
        colbase = col0 & 1023;
    }

    floatx4 acc[4][8];
    #pragma unroll
    for (int i = 0; i < 4; ++i)
        #pragma unroll
        for (int j = 0; j < 8; ++j) acc[i][j] = (floatx4){0.f, 0.f, 0.f, 0.f};

    const f16x8* pA = (const f16x8*)sA;
    const f16x8* pB = (const f16x8*)sB;

    // staging: 1024 chunks of 16B per array, 2 per thread per array
    int srow[2], scol[2];
    #pragma unroll
    for (int it = 0; it < 2; ++it) {
        const int n = tid + it * 512;
        srow[it] = n >> 2;
        scol[it] = (n & 3) ^ ((srow[it] >> 1) & 3);
    }

    for (int k0 = 0; k0 < K; k0 += 32) {
        #pragma unroll
        for (int it = 0; it < 2; ++it) {
            const int n = tid + it * 512;
            const size_t ga = (size_t)(row0 + srow[it]) * lda + (size_t)k0 + scol[it] * 8;
            const size_t gb = (size_t)(colbase + srow[it]) * ldb + (size_t)k0 + scol[it] * 8;
            gld16(A + ga, sA + n * 16);
            gld16(Bsrc + gb, sB + n * 16);
        }
        __syncthreads();

        f16x8 af[4];
        #pragma unroll
        for (int i = 0; i < 4; ++i) {
            const int r = wr * 64 + i * 16 + l16;
            af[i] = pA[r * 4 + (quad ^ swz)];
        }
        #pragma unroll
        for (int j = 0; j < 8; ++j) {
            const int c = wc * 128 + j * 16 + l16;
            const f16x8 bf = pB[c * 4 + (quad ^ swz)];
            #pragma unroll
            for (int i = 0; i < 4; ++i)
                acc[i][j] = __builtin_amdgcn_mfma_f32_16x16x32_f16(af[i], bf, acc[i][j], 0, 0, 0);
        }
        __syncthreads();
    }

    // ---- epilogue (C/D layout: col=lane&15, row=quad*4+reg) ----
    #pragma unroll
    for (int i = 0; i < 4; ++i) {
        const int r0 = row0 + wr * 64 + i * 16 + quad * 4;

        float rp[4] = {0.f, 0.f, 0.f, 0.f};             // MODE 3 row partials
        float linv[4];
        if (MODE == 4) {
            #pragma unroll
            for (int reg = 0; reg < 4; ++reg) linv[reg] = 1.0f / Lsum[r0 + reg];
        }

        #pragma unroll
        for (int j = 0; j < 8; ++j) {
            const int cl = (MODE == 5 ? colbase : col0) + wc * 128 + j * 16 + l16;

            if (MODE == 5) {
                const float bcol = (which == 0 ? bq : which == 1 ? bk : bv)[cl];
                if (which < 2) {
                    _Float16* O = (which == 0) ? Qo : Ko;
                    #pragma unroll
                    for (int reg = 0; reg < 4; ++reg)
                        O[(size_t)(r0 + reg) * HIDDEN + cl] =
                            (_Float16)(acc[i][j][reg] + bcol);
                } else {
                    const int bb = r0 >> 12;
                    const int s  = r0 & 4095;
                    _Float16 t[4];
                    #pragma unroll
                    for (int reg = 0; reg < 4; ++reg)
                        t[reg] = (_Float16)(acc[i][j][reg] + bcol);
                    *(uint2*)&Vo[((size_t)bb * HIDDEN + cl) * SEQ + s] = *(const uint2*)t;
                }
            } else if (MODE == 3) {
                #pragma unroll
                for (int reg = 0; reg < 4; ++reg) {
                    const float v = expf(alpha * acc[i][j][reg] - 4.0f);
                    const _Float16 vh = (_Float16)v;
                    Eo[(size_t)(r0 + reg) * SEQ + cl] = vh;
                    rp[reg] += (float)vh;
                }
            } else {  // MODE 4
                #pragma unroll
                for (int reg = 0; reg < 4; ++reg)
                    Cf[(size_t)(r0 + reg) * HIDDEN + cl] = acc[i][j][reg] * linv[reg];
            }
        }

        if (MODE == 3) {
            #pragma unroll
            for (int off = 1; off < 16; off <<= 1)
                #pragma unroll
                for (int reg = 0; reg < 4; ++reg)
                    rp[reg] += __shfl_xor(rp[reg], off, 64);
            if (l16 == 0)
                #pragma unroll
                for (int reg = 0; reg < 4; ++reg)
                    atomicAdd(&Lsum[r0 + reg], rp[reg]);
        }
    }
}

// ---------------------------------------------------------------------------
// fp32 -> fp16 cast, float4-vectorized
// ---------------------------------------------------------------------------
__global__ __launch_bounds__(256)
void cast_f16_kernel(const float* __restrict__ in, _Float16* __restrict__ out) {
    const int i = blockIdx.x * 256 + threadIdx.x;
    const float4 x = ((const float4*)in)[i];
    _Float16 h[4] = {(_Float16)x.x, (_Float16)x.y, (_Float16)x.z, (_Float16)x.w};
    ((uint2*)out)[i] = *(const uint2*)h;
}

// ---------------------------------------------------------------------------
// ws layout (bytes), total ~235 MB:
//   [0, 134.2M) : E fp16 [B][S][S]  (head aliases Xh + W casts, dead by then)
//   then        : Qh 33.5M | Kh 33.5M | Vt [B][H][S] 33.5M | Lsum 64K
// ---------------------------------------------------------------------------
extern "C" void kernel_launch(void* const* d_in, const int* in_sizes, int n_in,
                              void* d_out, int out_size, void* d_ws, size_t ws_size,
                              hipStream_t stream) {
    const float* X  = (const float*)d_in[0];
    const float* Wq = (const float*)d_in[1];
    const float* bq = (const float*)d_in[2];
    const float* Wk = (const float*)d_in[3];
    const float* bk = (const float*)d_in[4];
    const float* Wv = (const float*)d_in[5];
    const float* bv = (const float*)d_in[6];
    float* out = (float*)d_out;

    char* ws = (char*)d_ws;
    const size_t EB = (size_t)BATCH * SEQ * SEQ * 2;     // 134,217,728
    const size_t XB = (size_t)BATCH * SEQ * HIDDEN * 2;  // 33,554,432
    const size_t WB = (size_t)HIDDEN * HIDDEN * 2;       // 2,097,152

    _Float16* E   = (_Float16*)ws;
    _Float16* Xh  = (_Float16*)ws;                       // aliases E head
    _Float16* Wqh = (_Float16*)(ws + XB);
    _Float16* Wkh = (_Float16*)(ws + XB + WB);
    _Float16* Wvh = (_Float16*)(ws + XB + 2 * WB);
    _Float16* Qh  = (_Float16*)(ws + EB);
    _Float16* Kh  = (_Float16*)(ws + EB + XB);
    _Float16* Vt  = (_Float16*)(ws + EB + 2 * XB);       // [B][H][S]
    float*    Lsum= (float*)   (ws + EB + 3 * XB);       // [B][S]

    const dim3 blk512(512);

    // 1. casts
    cast_f16_kernel<<<dim3(16384), dim3(256), 0, stream>>>(X,  Xh);
    cast_f16_kernel<<<dim3(1024),  dim3(256), 0, stream>>>(Wq, Wqh);
    cast_f16_kernel<<<dim3(1024),  dim3(256), 0, stream>>>(Wk, Wkh);
    cast_f16_kernel<<<dim3(1024),  dim3(256), 0, stream>>>(Wv, Wvh);

    hipMemsetAsync(Lsum, 0, (size_t)BATCH * SEQ * sizeof(float), stream);

    // 2. fused QKV projection: [16384,1024] x [3072,1024]^T
    gemm256_kernel<5><<<dim3(12, 64, 1), blk512, 0, stream>>>(
        Xh, Wqh, Wkh, Wvh, bq, bk, bv, 1.0f,
        nullptr, nullptr, Qh, Kh, Vt, nullptr,
        HIDDEN, HIDDEN, HIDDEN);

    // 3. QK^T -> exp -> E (fp16) + row sums, all batches
    gemm256_kernel<3><<<dim3(16, 16, 4), blk512, 0, stream>>>(
        Qh, Kh, nullptr, nullptr, nullptr, nullptr, nullptr, 1.0f / 32.0f,
        nullptr, E, nullptr, nullptr, nullptr, Lsum,
        HIDDEN, HIDDEN, HIDDEN);

    // 4. PV with 1/Lsum scaling, all batches
    gemm256_kernel<4><<<dim3(4, 16, 4), blk512, 0, stream>>>(
        E, Vt, nullptr, nullptr, nullptr, nullptr, nullptr, 1.0f,
        out, nullptr, nullptr, nullptr, nullptr, Lsum,
        SEQ, SEQ, SEQ);
}